// Round 3
// baseline (1280.277 us; speedup 1.0000x reference)
//
// Round 3. Theory: SpMM atomics were 1335us (write-through 830MB/dispatch);
// replace with on-device CSR (hist+scan+scatter) and one-wave-per-row gather.
// Fuse 4 fp32 GEMMs (733us, MfmaUtil=0) into one bf16 MFMA GEMM over a
// packed [512][256] weight; col-block 0 -> d_out fp32, blocks 1-3 -> bf16 fw.
// ReLU fused into spmm epilogue. Tolerance is bf16-scale (0.4675) so bf16 ok.
#include <hip/hip_runtime.h>
#include <hip/hip_bf16.h>

#define F_DIM 256
#define D_DIM 128
#define NHOPS 3

using short8 = __attribute__((ext_vector_type(8))) short;
using f32x4  = __attribute__((ext_vector_type(4))) float;

// RNE float -> bf16 bits
static __device__ __forceinline__ unsigned short f2bf(float f) {
    unsigned int u = __float_as_uint(f);
    unsigned int r = (u + 0x7fffu + ((u >> 16) & 1u)) >> 16;
    return (unsigned short)r;
}

// ---- Wsum = alpha * sum_h W_embK[h]  [D][D] ----
__global__ void wsum_kernel(const float* __restrict__ W_embK,
                            const float* __restrict__ alpha,
                            float* __restrict__ Wsum) {
    int i = blockIdx.x * blockDim.x + threadIdx.x;
    if (i < D_DIM * D_DIM) {
        float a = alpha[0];
        Wsum[i] = a * (W_embK[i] + W_embK[D_DIM * D_DIM + i] + W_embK[2 * D_DIM * D_DIM + i]);
    }
}

// ---- Wc[F][D] = W_embed @ Wsum ----
__global__ void wc_kernel(const float* __restrict__ W_embed,
                          const float* __restrict__ Wsum,
                          float* __restrict__ Wc) {
    int i = blockIdx.x * blockDim.x + threadIdx.x;
    if (i < F_DIM * D_DIM) {
        int f = i / D_DIM, d = i % D_DIM;
        float acc = 0.f;
        #pragma unroll 8
        for (int k = 0; k < D_DIM; ++k)
            acc = fmaf(W_embed[f * D_DIM + k], Wsum[k * D_DIM + d], acc);
        Wc[i] = acc;
    }
}

// ---- Wt[512][256] bf16 = transpose of [Wc | W_feat0 | W_feat1 | W_feat2] ----
__global__ void pack_wt(const float* __restrict__ Wc,
                        const float* __restrict__ W_feat,
                        unsigned short* __restrict__ Wt) {
    int i = blockIdx.x * blockDim.x + threadIdx.x;   // 512*256
    int j = i >> 8, k = i & 255;                     // j = out col, k = in dim
    float v = (j < 128)
        ? Wc[k * D_DIM + j]
        : W_feat[(size_t)((j - 128) >> 7) * F_DIM * D_DIM + k * D_DIM + ((j - 128) & 127)];
    Wt[i] = f2bf(v);
}

// ---- histogram of row keys (key = hop*N + row) ----
__global__ void hist_kernel(const int* __restrict__ rows, int* __restrict__ counts,
                            int N, int E) {
    int idx = blockIdx.x * blockDim.x + threadIdx.x;
    int h = blockIdx.y;
    if (idx < E) atomicAdd(&counts[h * N + rows[(size_t)h * E + idx]], 1);
}

// ---- hierarchical exclusive scan over M=3N elements ----
__global__ void scan1(const int* __restrict__ counts, int* __restrict__ tmp,
                      int* __restrict__ bsums, int M) {
    __shared__ int s[256];
    int tid = threadIdx.x, i = blockIdx.x * 256 + tid;
    int v = (i < M) ? counts[i] : 0;
    s[tid] = v; __syncthreads();
    for (int off = 1; off < 256; off <<= 1) {
        int t = (tid >= off) ? s[tid - off] : 0;
        __syncthreads();
        s[tid] += t;
        __syncthreads();
    }
    if (i < M) tmp[i] = s[tid] - v;          // exclusive within block
    if (tid == 255) bsums[blockIdx.x] = s[255];
}

__global__ void scan2(int* __restrict__ bsums, int nb) {
    __shared__ int s[256];
    int tid = threadIdx.x;
    int carry = 0;
    for (int base = 0; base < nb; base += 256) {
        int v = (base + tid < nb) ? bsums[base + tid] : 0;
        s[tid] = v; __syncthreads();
        for (int off = 1; off < 256; off <<= 1) {
            int t = (tid >= off) ? s[tid - off] : 0;
            __syncthreads();
            s[tid] += t;
            __syncthreads();
        }
        if (base + tid < nb) bsums[base + tid] = carry + s[tid] - v;
        carry += s[255];
        __syncthreads();
    }
}

__global__ void scan3(int* __restrict__ tmp, const int* __restrict__ bsums,
                      int* __restrict__ offsets, int M, int total) {
    int i = blockIdx.x * blockDim.x + threadIdx.x;
    if (i < M) {
        int e = tmp[i] + bsums[i >> 8];
        offsets[i] = e;
        tmp[i] = e;          // tmp doubles as the scatter cursor array
    }
    if (i == 0) offsets[M] = total;
}

// ---- scatter edges into row-sorted order ----
__global__ void scatter_kernel(const int* __restrict__ rows, const int* __restrict__ cols,
                               const float* __restrict__ vals, int* __restrict__ cursors,
                               int2* __restrict__ cv, int N, int E) {
    int idx = blockIdx.x * blockDim.x + threadIdx.x;
    int h = blockIdx.y;
    if (idx < E) {
        size_t e = (size_t)h * E + idx;
        int r = rows[e];
        int p = atomicAdd(&cursors[h * N + r], 1);
        cv[p] = make_int2(cols[e], __float_as_int(vals[e]));
    }
}

// ---- fused bf16 MFMA GEMM: C[N][512] = X[N][256] @ Wt^T ----
// col-block 0 -> d_out fp32; col-block 1..3 -> fw[hop] bf16
__global__ __launch_bounds__(256) void gemm_mfma(const float* __restrict__ X,
                                                 const unsigned short* __restrict__ Wt,
                                                 float* __restrict__ out,
                                                 unsigned short* __restrict__ fw,
                                                 int N) {
    __shared__ __align__(16) unsigned short As[128][40];  // [m][k], pad to 40 shorts
    __shared__ __align__(16) unsigned short Bs[128][40];  // [n][k]

    const int tid = threadIdx.x;
    const int w = tid >> 6, lane = tid & 63;
    const int bm = blockIdx.x, bn = blockIdx.y;
    const int row0 = bm * 128;
    const int wm = (w & 1) * 64, wn = (w >> 1) * 64;
    const int l15 = lane & 15, lk = (lane >> 4) * 8;

    f32x4 acc[4][4] = {};

    for (int k0 = 0; k0 < F_DIM; k0 += 32) {
        // A: 128 rows x 32 k, fp32 -> bf16. 4 float4 per thread.
        float4 av[4];
        #pragma unroll
        for (int i = 0; i < 4; ++i) {
            int idx = tid + i * 256;            // 0..1023
            int ar = idx >> 3, kq = (idx & 7) << 2;
            int gr = row0 + ar; if (gr >= N) gr = N - 1;
            av[i] = *(const float4*)&X[(size_t)gr * F_DIM + k0 + kq];
        }
        // B: 128 n-rows x 32 k bf16 (Wt is [512][256] row-major, k contiguous)
        float4 bv[2];
        #pragma unroll
        for (int i = 0; i < 2; ++i) {
            int idx = tid + i * 256;            // 0..511
            int br = idx >> 2, kq = (idx & 3) << 3;
            bv[i] = *(const float4*)&Wt[((size_t)(bn * 128 + br)) * F_DIM + k0 + kq];
        }
        __syncthreads();
        #pragma unroll
        for (int i = 0; i < 4; ++i) {
            int idx = tid + i * 256;
            int ar = idx >> 3, kq = (idx & 7) << 2;
            ushort4 p;
            p.x = f2bf(av[i].x); p.y = f2bf(av[i].y);
            p.z = f2bf(av[i].z); p.w = f2bf(av[i].w);
            *(ushort4*)&As[ar][kq] = p;
        }
        #pragma unroll
        for (int i = 0; i < 2; ++i) {
            int idx = tid + i * 256;
            int br = idx >> 2, kq = (idx & 3) << 3;
            *(float4*)&Bs[br][kq] = bv[i];
        }
        __syncthreads();

        short8 af[4], bfr[4];
        #pragma unroll
        for (int mi = 0; mi < 4; ++mi) af[mi]  = *(const short8*)&As[wm + mi * 16 + l15][lk];
        #pragma unroll
        for (int ni = 0; ni < 4; ++ni) bfr[ni] = *(const short8*)&Bs[wn + ni * 16 + l15][lk];
        #pragma unroll
        for (int mi = 0; mi < 4; ++mi)
            #pragma unroll
            for (int ni = 0; ni < 4; ++ni)
                acc[mi][ni] = __builtin_amdgcn_mfma_f32_16x16x32_bf16(af[mi], bfr[ni], acc[mi][ni], 0, 0, 0);
        __syncthreads();
    }

    // epilogue: C/D layout col=lane&15, row=(lane>>4)*4+reg  (HW-verified)
    if (bn == 0) {
        #pragma unroll
        for (int mi = 0; mi < 4; ++mi) {
            int rowb = row0 + wm + mi * 16 + (lane >> 4) * 4;
            #pragma unroll
            for (int ni = 0; ni < 4; ++ni) {
                int col = wn + ni * 16 + l15;
                #pragma unroll
                for (int j = 0; j < 4; ++j) {
                    int rr = rowb + j;
                    if (rr < N) out[(size_t)rr * D_DIM + col] = acc[mi][ni][j];
                }
            }
        }
    } else {
        unsigned short* dst = fw + (size_t)(bn - 1) * N * D_DIM;
        #pragma unroll
        for (int mi = 0; mi < 4; ++mi) {
            int rowb = row0 + wm + mi * 16 + (lane >> 4) * 4;
            #pragma unroll
            for (int ni = 0; ni < 4; ++ni) {
                int col = wn + ni * 16 + l15;
                #pragma unroll
                for (int j = 0; j < 4; ++j) {
                    int rr = rowb + j;
                    if (rr < N) dst[(size_t)rr * D_DIM + col] = f2bf(acc[mi][ni][j]);
                }
            }
        }
    }
}

// ---- CSR SpMM: one wave per output row, all 3 hops, fused ReLU ----
__global__ __launch_bounds__(256) void spmm_csr(const int* __restrict__ off,
                                                const int2* __restrict__ cv,
                                                const unsigned short* __restrict__ fw,
                                                float* __restrict__ out, int N) {
    int w = threadIdx.x >> 6, lane = threadIdx.x & 63;
    int r = blockIdx.x * 4 + w;
    if (r >= N) return;
    size_t base = (size_t)r * D_DIM + lane * 2;
    float2 acc = *(const float2*)&out[base];
    #pragma unroll
    for (int h = 0; h < NHOPS; ++h) {
        const unsigned short* fwh = fw + (size_t)h * N * D_DIM;
        int s = off[h * N + r], e = off[h * N + r + 1];
        for (int i = s; i < e; ++i) {
            int2 ce = cv[i];
            float v = __int_as_float(ce.y);
            unsigned int p = *(const unsigned int*)&fwh[(size_t)ce.x * D_DIM + lane * 2];
            acc.x = fmaf(v, __uint_as_float(p << 16), acc.x);
            acc.y = fmaf(v, __uint_as_float(p & 0xffff0000u), acc.y);
        }
    }
    acc.x = fmaxf(acc.x, 0.f);
    acc.y = fmaxf(acc.y, 0.f);
    *(float2*)&out[base] = acc;
}

extern "C" void kernel_launch(void* const* d_in, const int* in_sizes, int n_in,
                              void* d_out, int out_size, void* d_ws, size_t ws_size,
                              hipStream_t stream) {
    const float* X         = (const float*)d_in[0];
    const int*   edge_rows = (const int*)d_in[1];
    const int*   edge_cols = (const int*)d_in[2];
    const float* edge_vals = (const float*)d_in[3];
    const float* W_embed   = (const float*)d_in[4];
    const float* W_feat    = (const float*)d_in[5];
    const float* W_embK    = (const float*)d_in[6];
    const float* alpha     = (const float*)d_in[7];
    float* out = (float*)d_out;

    const int N = in_sizes[0] / F_DIM;
    const int E = in_sizes[1] / NHOPS;
    const int M = NHOPS * N;

    // ---- workspace carve-up (256B aligned regions) ----
    char* wsb = (char*)d_ws;
    size_t o = 0;
    auto take = [&](size_t bytes) -> char* {
        char* p = wsb + o;
        o = (o + bytes + 255) & ~(size_t)255;
        return p;
    };
    int2*           cv      = (int2*)take((size_t)NHOPS * E * sizeof(int2));        // 38.4 MB
    unsigned short* fwb     = (unsigned short*)take((size_t)NHOPS * N * D_DIM * 2); // 76.8 MB
    int*            counts  = (int*)take((size_t)M * 4);
    int*            cursors = (int*)take((size_t)M * 4);
    int*            offsets = (int*)take((size_t)(M + 1) * 4);
    int*            bsums   = (int*)take(8192);
    float*          Wsum    = (float*)take(D_DIM * D_DIM * 4);
    float*          Wc      = (float*)take(F_DIM * D_DIM * 4);
    unsigned short* Wt      = (unsigned short*)take(512 * F_DIM * 2);
    (void)ws_size;

    // ---- CSR build ----
    hipMemsetAsync(counts, 0, (size_t)M * 4, stream);
    {
        dim3 g((E + 255) / 256, NHOPS);
        hist_kernel<<<g, 256, 0, stream>>>(edge_rows, counts, N, E);
    }
    int nb = (M + 255) / 256;
    scan1<<<nb, 256, 0, stream>>>(counts, cursors, bsums, M);
    scan2<<<1, 256, 0, stream>>>(bsums, nb);
    scan3<<<nb, 256, 0, stream>>>(cursors, bsums, offsets, M, NHOPS * E);
    {
        dim3 g((E + 255) / 256, NHOPS);
        scatter_kernel<<<g, 256, 0, stream>>>(edge_rows, edge_cols, edge_vals,
                                              cursors, cv, N, E);
    }

    // ---- weight prep ----
    wsum_kernel<<<(D_DIM * D_DIM + 255) / 256, 256, 0, stream>>>(W_embK, alpha, Wsum);
    wc_kernel<<<(F_DIM * D_DIM + 255) / 256, 256, 0, stream>>>(W_embed, Wsum, Wc);
    pack_wt<<<(512 * F_DIM) / 256, 256, 0, stream>>>(Wc, W_feat, Wt);

    // ---- fused GEMM: d_out = X@Wc (fp32), fw[h] = bf16(X@W_feat[h]) ----
    {
        dim3 g((N + 127) / 128, 4);
        gemm_mfma<<<g, 256, 0, stream>>>(X, Wt, out, fwb, N);
    }

    // ---- CSR SpMM + dense add + ReLU ----
    spmm_csr<<<(N + 3) / 4, 256, 0, stream>>>(offsets, cv, fwb, out, N);
}

// Round 4
// 1026.681 us; speedup vs baseline: 1.2470x; 1.2470x over previous
//
// Round 4. spmm_csr was 460us and LATENCY-bound (18% BW, 18% VALU, occ 81%):
// one serial gather chain per wave (~48 iters). Restructure: 4 edge-slots x
// 16 dim-lanes per wave, each slot strides edges by 4 and is unrolled x2 ->
// 8 outstanding 16B gathers/wave, serial depth ~6. shfl_xor(16,32) folds
// slots; slot 0 carries the dense init; ReLU fused. Rest unchanged.
#include <hip/hip_runtime.h>
#include <hip/hip_bf16.h>

#define F_DIM 256
#define D_DIM 128
#define NHOPS 3

using short8 = __attribute__((ext_vector_type(8))) short;
using f32x4  = __attribute__((ext_vector_type(4))) float;

// RNE float -> bf16 bits
static __device__ __forceinline__ unsigned short f2bf(float f) {
    unsigned int u = __float_as_uint(f);
    unsigned int r = (u + 0x7fffu + ((u >> 16) & 1u)) >> 16;
    return (unsigned short)r;
}

static __device__ __forceinline__ float bf2f(unsigned short b) {
    return __uint_as_float(((unsigned int)b) << 16);
}

// ---- Wsum = alpha * sum_h W_embK[h]  [D][D] ----
__global__ void wsum_kernel(const float* __restrict__ W_embK,
                            const float* __restrict__ alpha,
                            float* __restrict__ Wsum) {
    int i = blockIdx.x * blockDim.x + threadIdx.x;
    if (i < D_DIM * D_DIM) {
        float a = alpha[0];
        Wsum[i] = a * (W_embK[i] + W_embK[D_DIM * D_DIM + i] + W_embK[2 * D_DIM * D_DIM + i]);
    }
}

// ---- Wc[F][D] = W_embed @ Wsum ----
__global__ void wc_kernel(const float* __restrict__ W_embed,
                          const float* __restrict__ Wsum,
                          float* __restrict__ Wc) {
    int i = blockIdx.x * blockDim.x + threadIdx.x;
    if (i < F_DIM * D_DIM) {
        int f = i / D_DIM, d = i % D_DIM;
        float acc = 0.f;
        #pragma unroll 8
        for (int k = 0; k < D_DIM; ++k)
            acc = fmaf(W_embed[f * D_DIM + k], Wsum[k * D_DIM + d], acc);
        Wc[i] = acc;
    }
}

// ---- Wt[512][256] bf16 = transpose of [Wc | W_feat0 | W_feat1 | W_feat2] ----
__global__ void pack_wt(const float* __restrict__ Wc,
                        const float* __restrict__ W_feat,
                        unsigned short* __restrict__ Wt) {
    int i = blockIdx.x * blockDim.x + threadIdx.x;   // 512*256
    int j = i >> 8, k = i & 255;                     // j = out col, k = in dim
    float v = (j < 128)
        ? Wc[k * D_DIM + j]
        : W_feat[(size_t)((j - 128) >> 7) * F_DIM * D_DIM + k * D_DIM + ((j - 128) & 127)];
    Wt[i] = f2bf(v);
}

// ---- histogram of row keys (key = hop*N + row) ----
__global__ void hist_kernel(const int* __restrict__ rows, int* __restrict__ counts,
                            int N, int E) {
    int idx = blockIdx.x * blockDim.x + threadIdx.x;
    int h = blockIdx.y;
    if (idx < E) atomicAdd(&counts[h * N + rows[(size_t)h * E + idx]], 1);
}

// ---- hierarchical exclusive scan over M=3N elements ----
__global__ void scan1(const int* __restrict__ counts, int* __restrict__ tmp,
                      int* __restrict__ bsums, int M) {
    __shared__ int s[256];
    int tid = threadIdx.x, i = blockIdx.x * 256 + tid;
    int v = (i < M) ? counts[i] : 0;
    s[tid] = v; __syncthreads();
    for (int off = 1; off < 256; off <<= 1) {
        int t = (tid >= off) ? s[tid - off] : 0;
        __syncthreads();
        s[tid] += t;
        __syncthreads();
    }
    if (i < M) tmp[i] = s[tid] - v;          // exclusive within block
    if (tid == 255) bsums[blockIdx.x] = s[255];
}

__global__ void scan2(int* __restrict__ bsums, int nb) {
    __shared__ int s[256];
    int tid = threadIdx.x;
    int carry = 0;
    for (int base = 0; base < nb; base += 256) {
        int v = (base + tid < nb) ? bsums[base + tid] : 0;
        s[tid] = v; __syncthreads();
        for (int off = 1; off < 256; off <<= 1) {
            int t = (tid >= off) ? s[tid - off] : 0;
            __syncthreads();
            s[tid] += t;
            __syncthreads();
        }
        if (base + tid < nb) bsums[base + tid] = carry + s[tid] - v;
        carry += s[255];
        __syncthreads();
    }
}

__global__ void scan3(int* __restrict__ tmp, const int* __restrict__ bsums,
                      int* __restrict__ offsets, int M, int total) {
    int i = blockIdx.x * blockDim.x + threadIdx.x;
    if (i < M) {
        int e = tmp[i] + bsums[i >> 8];
        offsets[i] = e;
        tmp[i] = e;          // tmp doubles as the scatter cursor array
    }
    if (i == 0) offsets[M] = total;
}

// ---- scatter edges into row-sorted order ----
__global__ void scatter_kernel(const int* __restrict__ rows, const int* __restrict__ cols,
                               const float* __restrict__ vals, int* __restrict__ cursors,
                               int2* __restrict__ cv, int N, int E) {
    int idx = blockIdx.x * blockDim.x + threadIdx.x;
    int h = blockIdx.y;
    if (idx < E) {
        size_t e = (size_t)h * E + idx;
        int r = rows[e];
        int p = atomicAdd(&cursors[h * N + r], 1);
        cv[p] = make_int2(cols[e], __float_as_int(vals[e]));
    }
}

// ---- fused bf16 MFMA GEMM: C[N][512] = X[N][256] @ Wt^T ----
// col-block 0 -> d_out fp32; col-block 1..3 -> fw[hop] bf16
__global__ __launch_bounds__(256) void gemm_mfma(const float* __restrict__ X,
                                                 const unsigned short* __restrict__ Wt,
                                                 float* __restrict__ out,
                                                 unsigned short* __restrict__ fw,
                                                 int N) {
    __shared__ __align__(16) unsigned short As[128][40];  // [m][k], pad to 40 shorts
    __shared__ __align__(16) unsigned short Bs[128][40];  // [n][k]

    const int tid = threadIdx.x;
    const int w = tid >> 6, lane = tid & 63;
    const int bm = blockIdx.x, bn = blockIdx.y;
    const int row0 = bm * 128;
    const int wm = (w & 1) * 64, wn = (w >> 1) * 64;
    const int l15 = lane & 15, lk = (lane >> 4) * 8;

    f32x4 acc[4][4] = {};

    for (int k0 = 0; k0 < F_DIM; k0 += 32) {
        // A: 128 rows x 32 k, fp32 -> bf16. 4 float4 per thread.
        float4 av[4];
        #pragma unroll
        for (int i = 0; i < 4; ++i) {
            int idx = tid + i * 256;            // 0..1023
            int ar = idx >> 3, kq = (idx & 7) << 2;
            int gr = row0 + ar; if (gr >= N) gr = N - 1;
            av[i] = *(const float4*)&X[(size_t)gr * F_DIM + k0 + kq];
        }
        // B: 128 n-rows x 32 k bf16 (Wt is [512][256] row-major, k contiguous)
        float4 bv[2];
        #pragma unroll
        for (int i = 0; i < 2; ++i) {
            int idx = tid + i * 256;            // 0..511
            int br = idx >> 2, kq = (idx & 3) << 3;
            bv[i] = *(const float4*)&Wt[((size_t)(bn * 128 + br)) * F_DIM + k0 + kq];
        }
        __syncthreads();
        #pragma unroll
        for (int i = 0; i < 4; ++i) {
            int idx = tid + i * 256;
            int ar = idx >> 3, kq = (idx & 7) << 2;
            ushort4 p;
            p.x = f2bf(av[i].x); p.y = f2bf(av[i].y);
            p.z = f2bf(av[i].z); p.w = f2bf(av[i].w);
            *(ushort4*)&As[ar][kq] = p;
        }
        #pragma unroll
        for (int i = 0; i < 2; ++i) {
            int idx = tid + i * 256;
            int br = idx >> 2, kq = (idx & 3) << 3;
            *(float4*)&Bs[br][kq] = bv[i];
        }
        __syncthreads();

        short8 af[4], bfr[4];
        #pragma unroll
        for (int mi = 0; mi < 4; ++mi) af[mi]  = *(const short8*)&As[wm + mi * 16 + l15][lk];
        #pragma unroll
        for (int ni = 0; ni < 4; ++ni) bfr[ni] = *(const short8*)&Bs[wn + ni * 16 + l15][lk];
        #pragma unroll
        for (int mi = 0; mi < 4; ++mi)
            #pragma unroll
            for (int ni = 0; ni < 4; ++ni)
                acc[mi][ni] = __builtin_amdgcn_mfma_f32_16x16x32_bf16(af[mi], bfr[ni], acc[mi][ni], 0, 0, 0);
        __syncthreads();
    }

    // epilogue: C/D layout col=lane&15, row=(lane>>4)*4+reg  (HW-verified)
    if (bn == 0) {
        #pragma unroll
        for (int mi = 0; mi < 4; ++mi) {
            int rowb = row0 + wm + mi * 16 + (lane >> 4) * 4;
            #pragma unroll
            for (int ni = 0; ni < 4; ++ni) {
                int col = wn + ni * 16 + l15;
                #pragma unroll
                for (int j = 0; j < 4; ++j) {
                    int rr = rowb + j;
                    if (rr < N) out[(size_t)rr * D_DIM + col] = acc[mi][ni][j];
                }
            }
        }
    } else {
        unsigned short* dst = fw + (size_t)(bn - 1) * N * D_DIM;
        #pragma unroll
        for (int mi = 0; mi < 4; ++mi) {
            int rowb = row0 + wm + mi * 16 + (lane >> 4) * 4;
            #pragma unroll
            for (int ni = 0; ni < 4; ++ni) {
                int col = wn + ni * 16 + l15;
                #pragma unroll
                for (int j = 0; j < 4; ++j) {
                    int rr = rowb + j;
                    if (rr < N) dst[(size_t)rr * D_DIM + col] = f2bf(acc[mi][ni][j]);
                }
            }
        }
    }
}

// ---- CSR SpMM: one wave per row; 4 edge-slots x 16 dim-lanes; fused ReLU ----
__global__ __launch_bounds__(256) void spmm_csr(const int* __restrict__ off,
                                                const int2* __restrict__ cv,
                                                const unsigned short* __restrict__ fw,
                                                float* __restrict__ out, int N) {
    const int w = threadIdx.x >> 6, lane = threadIdx.x & 63;
    const int r = blockIdx.x * 4 + w;
    if (r >= N) return;
    const int sub = lane >> 4;       // edge slot 0..3
    const int dp  = lane & 15;       // dims dp*8 .. dp*8+7
    const size_t obase = (size_t)r * D_DIM + dp * 8;

    float acc[8];
    if (sub == 0) {
        float4 a = *(const float4*)&out[obase];
        float4 b = *(const float4*)&out[obase + 4];
        acc[0] = a.x; acc[1] = a.y; acc[2] = a.z; acc[3] = a.w;
        acc[4] = b.x; acc[5] = b.y; acc[6] = b.z; acc[7] = b.w;
    } else {
        #pragma unroll
        for (int j = 0; j < 8; ++j) acc[j] = 0.f;
    }

    #pragma unroll
    for (int h = 0; h < NHOPS; ++h) {
        const unsigned short* fwh = fw + (size_t)h * N * D_DIM;
        int s = off[h * N + r], e = off[h * N + r + 1];
        int i = s + sub;
        // unrolled x2: two independent gathers in flight per slot
        for (; i + 4 < e; i += 8) {
            int2 ca = cv[i];
            int2 cb = cv[i + 4];
            short8 pa = *(const short8*)&fwh[(size_t)ca.x * D_DIM + dp * 8];
            short8 pb = *(const short8*)&fwh[(size_t)cb.x * D_DIM + dp * 8];
            float va = __int_as_float(ca.y);
            float vb = __int_as_float(cb.y);
            #pragma unroll
            for (int j = 0; j < 8; ++j)
                acc[j] = fmaf(va, bf2f((unsigned short)pa[j]), acc[j]);
            #pragma unroll
            for (int j = 0; j < 8; ++j)
                acc[j] = fmaf(vb, bf2f((unsigned short)pb[j]), acc[j]);
        }
        if (i < e) {
            int2 ca = cv[i];
            short8 pa = *(const short8*)&fwh[(size_t)ca.x * D_DIM + dp * 8];
            float va = __int_as_float(ca.y);
            #pragma unroll
            for (int j = 0; j < 8; ++j)
                acc[j] = fmaf(va, bf2f((unsigned short)pa[j]), acc[j]);
        }
    }

    // fold the 4 edge slots
    #pragma unroll
    for (int j = 0; j < 8; ++j) {
        acc[j] += __shfl_xor(acc[j], 16, 64);
        acc[j] += __shfl_xor(acc[j], 32, 64);
    }

    if (sub == 0) {
        float4 a = {fmaxf(acc[0], 0.f), fmaxf(acc[1], 0.f), fmaxf(acc[2], 0.f), fmaxf(acc[3], 0.f)};
        float4 b = {fmaxf(acc[4], 0.f), fmaxf(acc[5], 0.f), fmaxf(acc[6], 0.f), fmaxf(acc[7], 0.f)};
        *(float4*)&out[obase]     = a;
        *(float4*)&out[obase + 4] = b;
    }
}

extern "C" void kernel_launch(void* const* d_in, const int* in_sizes, int n_in,
                              void* d_out, int out_size, void* d_ws, size_t ws_size,
                              hipStream_t stream) {
    const float* X         = (const float*)d_in[0];
    const int*   edge_rows = (const int*)d_in[1];
    const int*   edge_cols = (const int*)d_in[2];
    const float* edge_vals = (const float*)d_in[3];
    const float* W_embed   = (const float*)d_in[4];
    const float* W_feat    = (const float*)d_in[5];
    const float* W_embK    = (const float*)d_in[6];
    const float* alpha     = (const float*)d_in[7];
    float* out = (float*)d_out;

    const int N = in_sizes[0] / F_DIM;
    const int E = in_sizes[1] / NHOPS;
    const int M = NHOPS * N;

    // ---- workspace carve-up (256B aligned regions) ----
    char* wsb = (char*)d_ws;
    size_t o = 0;
    auto take = [&](size_t bytes) -> char* {
        char* p = wsb + o;
        o = (o + bytes + 255) & ~(size_t)255;
        return p;
    };
    int2*           cv      = (int2*)take((size_t)NHOPS * E * sizeof(int2));        // 38.4 MB
    unsigned short* fwb     = (unsigned short*)take((size_t)NHOPS * N * D_DIM * 2); // 76.8 MB
    int*            counts  = (int*)take((size_t)M * 4);
    int*            cursors = (int*)take((size_t)M * 4);
    int*            offsets = (int*)take((size_t)(M + 1) * 4);
    int*            bsums   = (int*)take(8192);
    float*          Wsum    = (float*)take(D_DIM * D_DIM * 4);
    float*          Wc      = (float*)take(F_DIM * D_DIM * 4);
    unsigned short* Wt      = (unsigned short*)take(512 * F_DIM * 2);
    (void)ws_size;

    // ---- CSR build ----
    hipMemsetAsync(counts, 0, (size_t)M * 4, stream);
    {
        dim3 g((E + 255) / 256, NHOPS);
        hist_kernel<<<g, 256, 0, stream>>>(edge_rows, counts, N, E);
    }
    int nb = (M + 255) / 256;
    scan1<<<nb, 256, 0, stream>>>(counts, cursors, bsums, M);
    scan2<<<1, 256, 0, stream>>>(bsums, nb);
    scan3<<<nb, 256, 0, stream>>>(cursors, bsums, offsets, M, NHOPS * E);
    {
        dim3 g((E + 255) / 256, NHOPS);
        scatter_kernel<<<g, 256, 0, stream>>>(edge_rows, edge_cols, edge_vals,
                                              cursors, cv, N, E);
    }

    // ---- weight prep ----
    wsum_kernel<<<(D_DIM * D_DIM + 255) / 256, 256, 0, stream>>>(W_embK, alpha, Wsum);
    wc_kernel<<<(F_DIM * D_DIM + 255) / 256, 256, 0, stream>>>(W_embed, Wsum, Wc);
    pack_wt<<<(512 * F_DIM) / 256, 256, 0, stream>>>(Wc, W_feat, Wt);

    // ---- fused GEMM: d_out = X@Wc (fp32), fw[h] = bf16(X@W_feat[h]) ----
    {
        dim3 g((N + 127) / 128, 4);
        gemm_mfma<<<g, 256, 0, stream>>>(X, Wt, out, fwb, N);
    }

    // ---- CSR SpMM + dense add + ReLU ----
    spmm_csr<<<(N + 3) / 4, 256, 0, stream>>>(offsets, cv, fwb, out, N);
}

// Round 5
// 662.215 us; speedup vs baseline: 1.9333x; 1.5504x over previous
//
// Round 5. scatter_kernel was 375us: WRITE_SIZE 299MB = 4.8M x 64B line
// allocations (random 8B writes, no L2 combining across WGs/XCDs). Replace
// hist+scan+scatter with two-pass bucket sort: pass1 bins edges into ~300
// coarse buckets (burst writes, L2-combined), pass2 = per-bucket LDS counting
// sort -> exact CSR offsets + row-sorted cv within an L2-resident 128KB
// window. Also pre-cast X to bf16 once (L3-resident) so the gemm's 4
// column-blocks re-read X from L3 not HBM. spmm unchanged. ws-tiered fallback.
#include <hip/hip_runtime.h>
#include <hip/hip_bf16.h>

#define F_DIM 256
#define D_DIM 128
#define NHOPS 3
#define KPB   1000     // row-keys per bucket
#define NBMAX 512      // max buckets supported by LDS arrays

using short8 = __attribute__((ext_vector_type(8))) short;
using f32x4  = __attribute__((ext_vector_type(4))) float;

static __device__ __forceinline__ unsigned short f2bf(float f) {
    unsigned int u = __float_as_uint(f);
    unsigned int r = (u + 0x7fffu + ((u >> 16) & 1u)) >> 16;
    return (unsigned short)r;
}
static __device__ __forceinline__ float bf2f(unsigned short b) {
    return __uint_as_float(((unsigned int)b) << 16);
}

// ---- Wsum = alpha * sum_h W_embK[h] ----
__global__ void wsum_kernel(const float* __restrict__ W_embK,
                            const float* __restrict__ alpha,
                            float* __restrict__ Wsum) {
    int i = blockIdx.x * blockDim.x + threadIdx.x;
    if (i < D_DIM * D_DIM) {
        float a = alpha[0];
        Wsum[i] = a * (W_embK[i] + W_embK[D_DIM * D_DIM + i] + W_embK[2 * D_DIM * D_DIM + i]);
    }
}

// ---- Wc = W_embed @ Wsum ----
__global__ void wc_kernel(const float* __restrict__ W_embed,
                          const float* __restrict__ Wsum,
                          float* __restrict__ Wc) {
    int i = blockIdx.x * blockDim.x + threadIdx.x;
    if (i < F_DIM * D_DIM) {
        int f = i / D_DIM, d = i % D_DIM;
        float acc = 0.f;
        #pragma unroll 8
        for (int k = 0; k < D_DIM; ++k)
            acc = fmaf(W_embed[f * D_DIM + k], Wsum[k * D_DIM + d], acc);
        Wc[i] = acc;
    }
}

// ---- Wt[512][256] bf16 = transpose of [Wc | W_feat0..2] ----
__global__ void pack_wt(const float* __restrict__ Wc,
                        const float* __restrict__ W_feat,
                        unsigned short* __restrict__ Wt) {
    int i = blockIdx.x * blockDim.x + threadIdx.x;
    int j = i >> 8, k = i & 255;
    float v = (j < 128)
        ? Wc[k * D_DIM + j]
        : W_feat[(size_t)((j - 128) >> 7) * F_DIM * D_DIM + k * D_DIM + ((j - 128) & 127)];
    Wt[i] = f2bf(v);
}

// ---- Xb = bf16(X), one pass ----
__global__ void xcast_kernel(const float* __restrict__ X, unsigned short* __restrict__ Xb,
                             int n4) {
    int i = blockIdx.x * blockDim.x + threadIdx.x;
    int stride = gridDim.x * blockDim.x;
    for (; i < n4; i += stride) {
        float4 v = ((const float4*)X)[i];
        ushort4 p;
        p.x = f2bf(v.x); p.y = f2bf(v.y); p.z = f2bf(v.z); p.w = f2bf(v.w);
        ((ushort4*)Xb)[i] = p;
    }
}

// ================= new sort pipeline =================

// bucket counts (coarse, NB ~ 300)
__global__ __launch_bounds__(256) void bhist_kernel(const int* __restrict__ rows,
                                                    int* __restrict__ bcount,
                                                    int N, int E, int TE) {
    __shared__ int h[NBMAX];
    int tid = threadIdx.x;
    for (int i = tid; i < NBMAX; i += 256) h[i] = 0;
    __syncthreads();
    int c0 = blockIdx.x * 4096;
    #pragma unroll
    for (int i = 0; i < 16; ++i) {
        int ge = c0 + tid + i * 256;
        if (ge < TE) {
            int row = rows[ge];
            int hp = (ge >= E) + (ge >= 2 * E);
            int key = hp * N + row;
            atomicAdd(&h[key / KPB], 1);
        }
    }
    __syncthreads();
    for (int b = tid; b < NBMAX; b += 256)
        if (h[b]) atomicAdd(&bcount[b], h[b]);
}

// serial scan over NB buckets (tiny) -> bstart[0..NB], gcur init
__global__ void bscan_kernel(const int* __restrict__ bcount, int* __restrict__ bstart,
                             int* __restrict__ gcur, int NB) {
    __shared__ int s[NBMAX + 1];
    int tid = threadIdx.x;
    for (int i = tid; i < NB; i += 256) s[i] = bcount[i];
    __syncthreads();
    if (tid == 0) {
        int run = 0;
        for (int i = 0; i < NB; ++i) { int c = s[i]; s[i] = run; run += c; }
        s[NB] = run;
    }
    __syncthreads();
    for (int i = tid; i <= NB; i += 256) {
        bstart[i] = s[i];
        if (i < NB) gcur[i] = s[i];
    }
}

// pass 1: bin edges into bucket-grouped cvb. rec = {col | lkey<<17, val}
__global__ __launch_bounds__(256) void bucket_scatter(const int* __restrict__ rows,
                                                      const int* __restrict__ cols,
                                                      const float* __restrict__ vals,
                                                      int* __restrict__ gcur,
                                                      int2* __restrict__ cvb,
                                                      int N, int E, int TE) {
    __shared__ int sh_hist[NBMAX];
    __shared__ int sh_gof[NBMAX];
    int tid = threadIdx.x;
    for (int i = tid; i < NBMAX; i += 256) sh_hist[i] = 0;
    __syncthreads();
    int c0 = blockIdx.x * 4096;
    unsigned meta[16];
    #pragma unroll
    for (int i = 0; i < 16; ++i) {
        int ge = c0 + tid + i * 256;
        unsigned m = 0;
        if (ge < TE) {
            int row = rows[ge];
            int hp = (ge >= E) + (ge >= 2 * E);
            int key = hp * N + row;
            int b = key / KPB;
            int lkey = key - b * KPB;
            int rank = atomicAdd(&sh_hist[b], 1);
            m = ((unsigned)lkey << 22) | ((unsigned)b << 13) | (unsigned)rank;
        }
        meta[i] = m;
    }
    __syncthreads();
    for (int b = tid; b < NBMAX; b += 256)
        if (sh_hist[b]) sh_gof[b] = atomicAdd(&gcur[b], sh_hist[b]);
    __syncthreads();
    #pragma unroll
    for (int i = 0; i < 16; ++i) {
        int ge = c0 + tid + i * 256;
        if (ge < TE) {
            unsigned m = meta[i];
            int rank = m & 8191;
            int b = (m >> 13) & 511;
            int lkey = m >> 22;
            int col = cols[ge];
            float v = vals[ge];
            cvb[sh_gof[b] + rank] = make_int2(col | (lkey << 17), __float_as_int(v));
        }
    }
}

// pass 2: per-bucket LDS counting sort -> offsets slice + row-sorted cv
__global__ __launch_bounds__(256) void local_sort(const int2* __restrict__ cvb,
                                                  const int* __restrict__ bstart,
                                                  int2* __restrict__ cv,
                                                  int* __restrict__ offsets,
                                                  int M, int TE, int NB) {
    __shared__ int h[1024];
    __shared__ int part[256];
    const int tid = threadIdx.x;
    const int b = blockIdx.x;
    const int s = bstart[b], e = bstart[b + 1];

    for (int k = tid; k < 1024; k += 256) h[k] = 0;
    __syncthreads();
    for (int i = s + tid; i < e; i += 256) {
        unsigned lkey = ((unsigned)cvb[i].x) >> 17;
        atomicAdd(&h[lkey], 1);
    }
    __syncthreads();
    // exclusive scan over h[0..1023]
    int base4 = tid * 4;
    int a0 = h[base4], a1 = h[base4 + 1], a2 = h[base4 + 2], a3 = h[base4 + 3];
    part[tid] = a0 + a1 + a2 + a3;
    __syncthreads();
    for (int off = 1; off < 256; off <<= 1) {
        int t = (tid >= off) ? part[tid - off] : 0;
        __syncthreads();
        part[tid] += t;
        __syncthreads();
    }
    int pbase = tid ? part[tid - 1] : 0;
    h[base4]     = pbase;
    h[base4 + 1] = pbase + a0;
    h[base4 + 2] = pbase + a0 + a1;
    h[base4 + 3] = pbase + a0 + a1 + a2;
    __syncthreads();
    // emit CSR offsets for this bucket's keys
    for (int k = tid; k < KPB; k += 256) {
        int key = b * KPB + k;
        if (key < M) offsets[key] = s + h[k];
    }
    if (b == NB - 1 && tid == 0) offsets[M] = TE;
    __syncthreads();
    // scatter to final row-sorted positions (L2-resident window)
    for (int i = s + tid; i < e; i += 256) {
        int2 rec = cvb[i];
        unsigned lkey = ((unsigned)rec.x) >> 17;
        int p = s + atomicAdd(&h[lkey], 1);
        cv[p] = make_int2(rec.x & 0x1FFFF, rec.y);
    }
}

// ================= fallback (round-4) sort pipeline =================

__global__ void hist_kernel(const int* __restrict__ rows, int* __restrict__ counts,
                            int N, int E) {
    int idx = blockIdx.x * blockDim.x + threadIdx.x;
    int h = blockIdx.y;
    if (idx < E) atomicAdd(&counts[h * N + rows[(size_t)h * E + idx]], 1);
}

__global__ void scan1(const int* __restrict__ counts, int* __restrict__ tmp,
                      int* __restrict__ bsums, int M) {
    __shared__ int s[256];
    int tid = threadIdx.x, i = blockIdx.x * 256 + tid;
    int v = (i < M) ? counts[i] : 0;
    s[tid] = v; __syncthreads();
    for (int off = 1; off < 256; off <<= 1) {
        int t = (tid >= off) ? s[tid - off] : 0;
        __syncthreads();
        s[tid] += t;
        __syncthreads();
    }
    if (i < M) tmp[i] = s[tid] - v;
    if (tid == 255) bsums[blockIdx.x] = s[255];
}

__global__ void scan2(int* __restrict__ bsums, int nb) {
    __shared__ int s[256];
    int tid = threadIdx.x;
    int carry = 0;
    for (int base = 0; base < nb; base += 256) {
        int v = (base + tid < nb) ? bsums[base + tid] : 0;
        s[tid] = v; __syncthreads();
        for (int off = 1; off < 256; off <<= 1) {
            int t = (tid >= off) ? s[tid - off] : 0;
            __syncthreads();
            s[tid] += t;
            __syncthreads();
        }
        if (base + tid < nb) bsums[base + tid] = carry + s[tid] - v;
        carry += s[255];
        __syncthreads();
    }
}

__global__ void scan3(int* __restrict__ tmp, const int* __restrict__ bsums,
                      int* __restrict__ offsets, int M, int total) {
    int i = blockIdx.x * blockDim.x + threadIdx.x;
    if (i < M) {
        int e = tmp[i] + bsums[i >> 8];
        offsets[i] = e;
        tmp[i] = e;
    }
    if (i == 0) offsets[M] = total;
}

__global__ void scatter_kernel(const int* __restrict__ rows, const int* __restrict__ cols,
                               const float* __restrict__ vals, int* __restrict__ cursors,
                               int2* __restrict__ cv, int N, int E) {
    int idx = blockIdx.x * blockDim.x + threadIdx.x;
    int h = blockIdx.y;
    if (idx < E) {
        size_t e = (size_t)h * E + idx;
        int r = rows[e];
        int p = atomicAdd(&cursors[h * N + r], 1);
        cv[p] = make_int2(cols[e], __float_as_int(vals[e]));
    }
}

// ================= GEMM =================
// C[N][512] = X[N][256] @ Wt^T; bn 0 -> d_out fp32, bn 1..3 -> fw bf16
template <bool BF16A>
__global__ __launch_bounds__(256) void gemm_mfma(const float* __restrict__ X,
                                                 const unsigned short* __restrict__ Xb,
                                                 const unsigned short* __restrict__ Wt,
                                                 float* __restrict__ out,
                                                 unsigned short* __restrict__ fw,
                                                 int N) {
    __shared__ __align__(16) unsigned short As[128][40];
    __shared__ __align__(16) unsigned short Bs[128][40];

    const int tid = threadIdx.x;
    const int w = tid >> 6, lane = tid & 63;
    const int bm = blockIdx.x, bn = blockIdx.y;
    const int row0 = bm * 128;
    const int wm = (w & 1) * 64, wn = (w >> 1) * 64;
    const int l15 = lane & 15, lk = (lane >> 4) * 8;

    f32x4 acc[4][4] = {};

    for (int k0 = 0; k0 < F_DIM; k0 += 32) {
        float4 bv[2];
        #pragma unroll
        for (int i = 0; i < 2; ++i) {
            int idx = tid + i * 256;
            int br = idx >> 2, kq = (idx & 3) << 3;
            bv[i] = *(const float4*)&Wt[((size_t)(bn * 128 + br)) * F_DIM + k0 + kq];
        }
        if constexpr (BF16A) {
            short8 av[2];
            #pragma unroll
            for (int i = 0; i < 2; ++i) {
                int idx = tid + i * 256;
                int ar = idx >> 2, kq = (idx & 3) << 3;
                int gr = row0 + ar; if (gr >= N) gr = N - 1;
                av[i] = *(const short8*)&Xb[(size_t)gr * F_DIM + k0 + kq];
            }
            __syncthreads();
            #pragma unroll
            for (int i = 0; i < 2; ++i) {
                int idx = tid + i * 256;
                int ar = idx >> 2, kq = (idx & 3) << 3;
                *(short8*)&As[ar][kq] = av[i];
            }
        } else {
            float4 av[4];
            #pragma unroll
            for (int i = 0; i < 4; ++i) {
                int idx = tid + i * 256;
                int ar = idx >> 3, kq = (idx & 7) << 2;
                int gr = row0 + ar; if (gr >= N) gr = N - 1;
                av[i] = *(const float4*)&X[(size_t)gr * F_DIM + k0 + kq];
            }
            __syncthreads();
            #pragma unroll
            for (int i = 0; i < 4; ++i) {
                int idx = tid + i * 256;
                int ar = idx >> 3, kq = (idx & 7) << 2;
                ushort4 p;
                p.x = f2bf(av[i].x); p.y = f2bf(av[i].y);
                p.z = f2bf(av[i].z); p.w = f2bf(av[i].w);
                *(ushort4*)&As[ar][kq] = p;
            }
        }
        #pragma unroll
        for (int i = 0; i < 2; ++i) {
            int idx = tid + i * 256;
            int br = idx >> 2, kq = (idx & 3) << 3;
            *(float4*)&Bs[br][kq] = bv[i];
        }
        __syncthreads();

        short8 af[4], bfr[4];
        #pragma unroll
        for (int mi = 0; mi < 4; ++mi) af[mi]  = *(const short8*)&As[wm + mi * 16 + l15][lk];
        #pragma unroll
        for (int ni = 0; ni < 4; ++ni) bfr[ni] = *(const short8*)&Bs[wn + ni * 16 + l15][lk];
        #pragma unroll
        for (int mi = 0; mi < 4; ++mi)
            #pragma unroll
            for (int ni = 0; ni < 4; ++ni)
                acc[mi][ni] = __builtin_amdgcn_mfma_f32_16x16x32_bf16(af[mi], bfr[ni], acc[mi][ni], 0, 0, 0);
        __syncthreads();
    }

    if (bn == 0) {
        #pragma unroll
        for (int mi = 0; mi < 4; ++mi) {
            int rowb = row0 + wm + mi * 16 + (lane >> 4) * 4;
            #pragma unroll
            for (int ni = 0; ni < 4; ++ni) {
                int col = wn + ni * 16 + l15;
                #pragma unroll
                for (int j = 0; j < 4; ++j) {
                    int rr = rowb + j;
                    if (rr < N) out[(size_t)rr * D_DIM + col] = acc[mi][ni][j];
                }
            }
        }
    } else {
        unsigned short* dst = fw + (size_t)(bn - 1) * N * D_DIM;
        #pragma unroll
        for (int mi = 0; mi < 4; ++mi) {
            int rowb = row0 + wm + mi * 16 + (lane >> 4) * 4;
            #pragma unroll
            for (int ni = 0; ni < 4; ++ni) {
                int col = wn + ni * 16 + l15;
                #pragma unroll
                for (int j = 0; j < 4; ++j) {
                    int rr = rowb + j;
                    if (rr < N) dst[(size_t)rr * D_DIM + col] = f2bf(acc[mi][ni][j]);
                }
            }
        }
    }
}

// ---- CSR SpMM: wave per row; 4 edge-slots x 16 dim-lanes; fused ReLU ----
__global__ __launch_bounds__(256) void spmm_csr(const int* __restrict__ off,
                                                const int2* __restrict__ cv,
                                                const unsigned short* __restrict__ fw,
                                                float* __restrict__ out, int N) {
    const int w = threadIdx.x >> 6, lane = threadIdx.x & 63;
    const int r = blockIdx.x * 4 + w;
    if (r >= N) return;
    const int sub = lane >> 4;
    const int dp  = lane & 15;
    const size_t obase = (size_t)r * D_DIM + dp * 8;

    float acc[8];
    if (sub == 0) {
        float4 a = *(const float4*)&out[obase];
        float4 b = *(const float4*)&out[obase + 4];
        acc[0] = a.x; acc[1] = a.y; acc[2] = a.z; acc[3] = a.w;
        acc[4] = b.x; acc[5] = b.y; acc[6] = b.z; acc[7] = b.w;
    } else {
        #pragma unroll
        for (int j = 0; j < 8; ++j) acc[j] = 0.f;
    }

    #pragma unroll
    for (int h = 0; h < NHOPS; ++h) {
        const unsigned short* fwh = fw + (size_t)h * N * D_DIM;
        int s = off[h * N + r], e = off[h * N + r + 1];
        int i = s + sub;
        for (; i + 4 < e; i += 8) {
            int2 ca = cv[i];
            int2 cb = cv[i + 4];
            short8 pa = *(const short8*)&fwh[(size_t)ca.x * D_DIM + dp * 8];
            short8 pb = *(const short8*)&fwh[(size_t)cb.x * D_DIM + dp * 8];
            float va = __int_as_float(ca.y);
            float vb = __int_as_float(cb.y);
            #pragma unroll
            for (int j = 0; j < 8; ++j)
                acc[j] = fmaf(va, bf2f((unsigned short)pa[j]), acc[j]);
            #pragma unroll
            for (int j = 0; j < 8; ++j)
                acc[j] = fmaf(vb, bf2f((unsigned short)pb[j]), acc[j]);
        }
        if (i < e) {
            int2 ca = cv[i];
            short8 pa = *(const short8*)&fwh[(size_t)ca.x * D_DIM + dp * 8];
            float va = __int_as_float(ca.y);
            #pragma unroll
            for (int j = 0; j < 8; ++j)
                acc[j] = fmaf(va, bf2f((unsigned short)pa[j]), acc[j]);
        }
    }

    #pragma unroll
    for (int j = 0; j < 8; ++j) {
        acc[j] += __shfl_xor(acc[j], 16, 64);
        acc[j] += __shfl_xor(acc[j], 32, 64);
    }

    if (sub == 0) {
        float4 a = {fmaxf(acc[0], 0.f), fmaxf(acc[1], 0.f), fmaxf(acc[2], 0.f), fmaxf(acc[3], 0.f)};
        float4 b = {fmaxf(acc[4], 0.f), fmaxf(acc[5], 0.f), fmaxf(acc[6], 0.f), fmaxf(acc[7], 0.f)};
        *(float4*)&out[obase]     = a;
        *(float4*)&out[obase + 4] = b;
    }
}

extern "C" void kernel_launch(void* const* d_in, const int* in_sizes, int n_in,
                              void* d_out, int out_size, void* d_ws, size_t ws_size,
                              hipStream_t stream) {
    const float* X         = (const float*)d_in[0];
    const int*   edge_rows = (const int*)d_in[1];
    const int*   edge_cols = (const int*)d_in[2];
    const float* edge_vals = (const float*)d_in[3];
    const float* W_embed   = (const float*)d_in[4];
    const float* W_feat    = (const float*)d_in[5];
    const float* W_embK    = (const float*)d_in[6];
    const float* alpha     = (const float*)d_in[7];
    float* out = (float*)d_out;

    const int N  = in_sizes[0] / F_DIM;
    const int E  = in_sizes[1] / NHOPS;
    const int M  = NHOPS * N;
    const int TE = NHOPS * E;
    const int NB = (M + KPB - 1) / KPB;

    auto al = [](size_t x) { return (x + 255) & ~(size_t)255; };
    const size_t sz_cv   = al((size_t)TE * 8);
    const size_t sz_fwb  = al((size_t)M * D_DIM * 2);
    const size_t sz_xb   = al((size_t)N * F_DIM * 2);
    const size_t sz_off  = al((size_t)(M + 1) * 4);
    const size_t sz_m    = al((size_t)M * 4);
    const size_t sz_b    = al((size_t)(NBMAX + 1) * 4);
    const size_t sz_w    = al(D_DIM * D_DIM * 4) + al(F_DIM * D_DIM * 4) + al(512 * F_DIM * 2);
    const size_t need_mid = 2 * sz_cv + sz_fwb + sz_off + 3 * sz_b + sz_w;
    const size_t need_big = need_mid + sz_xb;

    const bool ok_new = (NB <= NBMAX) && (N < (1 << 17));
    const int mode = (ok_new && ws_size >= need_big) ? 2
                   : (ok_new && ws_size >= need_mid) ? 1 : 0;

    char* wsb = (char*)d_ws;
    size_t o = 0;
    auto take = [&](size_t bytes) -> char* {
        char* p = wsb + o;
        o += al(bytes);
        return p;
    };

    if (mode >= 1) {
        int2*           cvb     = (int2*)take((size_t)TE * 8);
        int2*           cv      = (int2*)take((size_t)TE * 8);
        unsigned short* fwb     = (unsigned short*)take((size_t)M * D_DIM * 2);
        int*            offsets = (int*)take((size_t)(M + 1) * 4);
        int*            bcount  = (int*)take((NBMAX + 1) * 4);
        int*            bstart  = (int*)take((NBMAX + 1) * 4);
        int*            gcur    = (int*)take((NBMAX + 1) * 4);
        float*          Wsum    = (float*)take(D_DIM * D_DIM * 4);
        float*          Wc      = (float*)take(F_DIM * D_DIM * 4);
        unsigned short* Wt      = (unsigned short*)take(512 * F_DIM * 2);
        unsigned short* Xb      = (mode == 2) ? (unsigned short*)take((size_t)N * F_DIM * 2) : nullptr;

        const int nchunk = (TE + 4095) / 4096;
        hipMemsetAsync(bcount, 0, NBMAX * 4, stream);
        bhist_kernel<<<nchunk, 256, 0, stream>>>(edge_rows, bcount, N, E, TE);
        bscan_kernel<<<1, 256, 0, stream>>>(bcount, bstart, gcur, NB);
        bucket_scatter<<<nchunk, 256, 0, stream>>>(edge_rows, edge_cols, edge_vals,
                                                   gcur, cvb, N, E, TE);
        local_sort<<<NB, 256, 0, stream>>>(cvb, bstart, cv, offsets, M, TE, NB);

        wsum_kernel<<<(D_DIM * D_DIM + 255) / 256, 256, 0, stream>>>(W_embK, alpha, Wsum);
        wc_kernel<<<(F_DIM * D_DIM + 255) / 256, 256, 0, stream>>>(W_embed, Wsum, Wc);
        pack_wt<<<(512 * F_DIM) / 256, 256, 0, stream>>>(Wc, W_feat, Wt);

        dim3 g((N + 127) / 128, 4);
        if (mode == 2) {
            xcast_kernel<<<2048, 256, 0, stream>>>(X, Xb, N * F_DIM / 4);
            gemm_mfma<true><<<g, 256, 0, stream>>>(X, Xb, Wt, out, fwb, N);
        } else {
            gemm_mfma<false><<<g, 256, 0, stream>>>(X, nullptr, Wt, out, fwb, N);
        }

        spmm_csr<<<(N + 3) / 4, 256, 0, stream>>>(offsets, cv, fwb, out, N);
    } else {
        // round-4 fallback
        int2*           cv      = (int2*)take((size_t)TE * 8);
        unsigned short* fwb     = (unsigned short*)take((size_t)M * D_DIM * 2);
        int*            counts  = (int*)take((size_t)M * 4);
        int*            cursors = (int*)take((size_t)M * 4);
        int*            offsets = (int*)take((size_t)(M + 1) * 4);
        int*            bsums   = (int*)take(8192);
        float*          Wsum    = (float*)take(D_DIM * D_DIM * 4);
        float*          Wc      = (float*)take(F_DIM * D_DIM * 4);
        unsigned short* Wt      = (unsigned short*)take(512 * F_DIM * 2);

        hipMemsetAsync(counts, 0, (size_t)M * 4, stream);
        dim3 ge((E + 255) / 256, NHOPS);
        hist_kernel<<<ge, 256, 0, stream>>>(edge_rows, counts, N, E);
        int nb = (M + 255) / 256;
        scan1<<<nb, 256, 0, stream>>>(counts, cursors, bsums, M);
        scan2<<<1, 256, 0, stream>>>(bsums, nb);
        scan3<<<nb, 256, 0, stream>>>(cursors, bsums, offsets, M, TE);
        scatter_kernel<<<ge, 256, 0, stream>>>(edge_rows, edge_cols, edge_vals,
                                               cursors, cv, N, E);

        wsum_kernel<<<(D_DIM * D_DIM + 255) / 256, 256, 0, stream>>>(W_embK, alpha, Wsum);
        wc_kernel<<<(F_DIM * D_DIM + 255) / 256, 256, 0, stream>>>(W_embed, Wsum, Wc);
        pack_wt<<<(512 * F_DIM) / 256, 256, 0, stream>>>(Wc, W_feat, Wt);

        dim3 g((N + 127) / 128, 4);
        gemm_mfma<false><<<g, 256, 0, stream>>>(X, nullptr, Wt, out, fwb, N);

        spmm_csr<<<(N + 3) / 4, 256, 0, stream>>>(offsets, cv, fwb, out, N);
    }
}